// Round 11
// baseline (185.581 us; speedup 1.0000x reference)
//
#include <hip/hip_runtime.h>

// DenseCRF-RNN fwd, D=64,H=128,W=128, L=2, 5 iters — 6 launches (R6 structure).
// q1 = sigmoid(cur1-cur0); delta = P - Ac*blur3d(q) - M*num(q);
// num = sum_27 w255_o(x)*q(x+d_o), u8 weights (tile-blocked, coalesced).
// R11 (iter only; pre = R6 verbatim):
//  - q tile in LDS as fp16 (5.8 KB) + t1 padded rows (11.5 KB); t2 REMOVED
//    (blur-y and blur-z merged into one 25-tap phase) -> LDS 26.9->17.3 KB.
//  - __launch_bounds__(256,6): 85 VGPR cap -> 6 blocks/CU (24 waves), all
//    1024 blocks co-resident. Barriers 4 -> 3. W read inline (no prefetch).
// ws: qA | qB | P | M (f32, NN+264 apart) | W u8 28.3 MB  (~45 MB).

#define DD 64
#define HH 128
#define WW 128
#define NN (DD*HH*WW)   // 1048576
#define PAD 264
#define TILE_WU 6912    // u32 per tile weight block: 27 * 256

typedef _Float16 hf;
typedef _Float16 hf4 __attribute__((ext_vector_type(4)));

__device__ __forceinline__ float bfac(int p, int dim) {
    const float K[5] = {0.05448868f, 0.24420134f, 0.40261995f, 0.24420134f, 0.05448868f};
    float s = 0.f;
#pragma unroll
    for (int o = -2; o <= 2; ++o) {
        int pp = p + o;
        s += (pp >= 0 && pp < dim) ? K[o + 2] : 0.f;
    }
    return s;
}

__device__ __forceinline__ void ldrow(const float* p, float* r) {
    float4 a = *(const float4*)p;
    float4 b = *(const float4*)(p + 4);
    r[0] = a.x; r[1] = a.y; r[2] = a.z; r[3] = a.w;
    r[4] = b.x; r[5] = b.y; r[6] = b.z; r[7] = b.w;
}

// ======================= pre: R6 verbatim ===================================
// Tile 8z x 8y x 16x, 256 threads, 4 x-voxels/thread (same as crf_iter).
__global__ __launch_bounds__(256) void crf_pre(
    const float* __restrict__ img, const float* __restrict__ h,
    const float* __restrict__ f1, const float* __restrict__ w0,
    const float* __restrict__ sw, const float* __restrict__ bw,
    const float* __restrict__ cm,
    float* __restrict__ qA, float* __restrict__ P,
    float* __restrict__ M, unsigned int* __restrict__ W)
{
    const float Sc[4] = {1.f, 0.80073740f, 0.64118039f, 0.51341712f};
    __shared__ float ims[10][10][20];

    const int tid = threadIdx.x;
    const int x0 = blockIdx.x * 16, y0 = blockIdx.y * 8, z0 = blockIdx.z * 8;
    const int T = ((int)blockIdx.z * 16 + (int)blockIdx.y) * 8 + (int)blockIdx.x;

    float* imf = &ims[0][0][0];
    for (int idx = tid; idx < 2000; idx += 256) {
        int lz2 = idx / 200, r = idx - lz2 * 200, ly2 = r / 20, lx2 = r - ly2 * 20;
        int gz = z0 + lz2 - 1, gy = y0 + ly2 - 1, gx = x0 + lx2 - 1;
        float v = 0.f;
        if ((unsigned)gz < 64u && (unsigned)gy < 128u && (unsigned)gx < 128u)
            v = img[(gz << 14) + (gy << 7) + gx];
        imf[idx] = v;
    }
    __syncthreads();

    const int lx = (tid & 3) * 4, ly = (tid >> 2) & 7, lz = tid >> 5;
    const int x = x0 + lx, y = y0 + ly, z = z0 + lz;
    const int g = (z << 14) + (y << 7) + x;

    const float cd0 = cm[2] - cm[0], cd1 = cm[3] - cm[1];
    const float Ksp = cd0 * sw[0] + cd1 * sw[2];
    const float Kbl = cd0 * bw[0] + cd1 * bw[2];
    const float Bc  = cd0 * (bw[1] - bw[0]) + cd1 * (bw[3] - bw[2]);

    float rowC[8];
    ldrow(&ims[lz + 1][ly + 1][lx], rowC);
    const float Ic[4] = {rowC[1], rowC[2], rowC[3], rowC[4]};

    float den[4] = {0.f, 0.f, 0.f, 0.f}, numi[4] = {0.f, 0.f, 0.f, 0.f};
    unsigned int* __restrict__ Wt = W + T * TILE_WU;

    float rI[8];
#pragma unroll
    for (int r9 = 0; r9 < 9; ++r9) {
        const int dz = r9 / 3 - 1, dy = r9 % 3 - 1;
        ldrow(&ims[lz + 1 + dz][ly + 1 + dy][lx], rI);
        const bool zyin = ((unsigned)(z + dz) < 64u) && ((unsigned)(y + dy) < 128u);
#pragma unroll
        for (int c = 0; c < 3; ++c) {
            const int dx = c - 1;
            const float s = Sc[dz * dz + dy * dy + dx * dx];
            unsigned pack = 0;
#pragma unroll
            for (int xi = 0; xi < 4; ++xi) {
                float dd = Ic[xi] - rI[xi + c];
                float w = s * __expf(-2.f * dd * dd);
                den[xi] += w;
                bool inb = zyin && ((unsigned)(x + xi + dx) < 128u);
                numi[xi] += inb ? w : 0.f;
                pack |= ((unsigned)(w * 255.f + 0.5f)) << (8 * xi);
            }
            Wt[(r9 * 3 + c) * 256 + tid] = pack;   // 256-B contiguous per wave
        }
    }

    float4 h0v = *(const float4*)&h[g];
    float4 h1v = *(const float4*)&h[NN + g];
    float4 f1v = *(const float4*)&f1[g];
    const float w00 = w0[0];
    const float bz = bfac(z, 64), by = bfac(y, 128);
    float hh0[4] = {h0v.x, h0v.y, h0v.z, h0v.w};
    float hh1[4] = {h1v.x, h1v.y, h1v.z, h1v.w};
    float ff[4]  = {f1v.x, f1v.y, f1v.z, f1v.w};
    float qv[4], Pv[4], Mv[4];
#pragma unroll
    for (int xi = 0; xi < 4; ++xi) {
        float dq = hh1[xi] - hh0[xi];
        float logp = -0.5f * Ic[xi] * Ic[xi] - 0.91893853320467274f;
        float t = -(w00 + logp - ff[xi]);
        float bones = bz * by * bfac(x + xi, 128);
        qv[xi] = 1.f / (1.f + __expf(-dq));
        Pv[xi] = dq * t - Ksp * bones - Kbl * (numi[xi] / den[xi]);
        Mv[xi] = Bc / (den[xi] * 255.f);
    }
    *(float4*)&qA[g] = {qv[0], qv[1], qv[2], qv[3]};
    *(float4*)&P[g]  = {Pv[0], Pv[1], Pv[2], Pv[3]};
    *(float4*)&M[g]  = {Mv[0], Mv[1], Mv[2], Mv[3]};
}

// ======================= iter: fp16 q LDS, merged yz-blur ===================
// Tile: 8z x 8y x 16x outputs per block, 256 threads, 4 x-voxels/thread.
template <bool LAST>
__global__ __launch_bounds__(256, 6) void crf_iter(
    const float* __restrict__ qsrc, float* __restrict__ qdst,
    const float* __restrict__ P, const float* __restrict__ M,
    const unsigned int* __restrict__ W,
    const float* __restrict__ sw, const float* __restrict__ cm,
    const float* __restrict__ f1, float* __restrict__ out)
{
    const float K0 = 0.05448868f, K1 = 0.24420134f, K2 = 0.40261995f;
    const float Kz[5] = {K0, K1, K2, K1, K0};

    __shared__ hf    qsH[12][12][20];  // q tile fp16, halo 2 (5.8 KB)
    __shared__ float t1[12][12][20];   // blur-x, padded rows (11.5 KB)

    const int tid = threadIdx.x;
    const int x0 = blockIdx.x * 16, y0 = blockIdx.y * 8, zB = blockIdx.z * 8;
    const int T = ((int)blockIdx.z * 16 + (int)blockIdx.y) * 8 + (int)blockIdx.x;
    const int lx = (tid & 3) * 4, ly = (tid >> 2) & 7, lz = tid >> 5;
    const int g = ((zB + lz) << 14) + ((y0 + ly) << 7) + (x0 + lx);

    const float cd0 = cm[2] - cm[0], cd1 = cm[3] - cm[1];
    const float Ac = cd0 * (sw[1] - sw[0]) + cd1 * (sw[3] - sw[2]);

    // stage q (halo 2) as fp16
    hf* qf = &qsH[0][0][0];
    for (int idx = tid; idx < 2880; idx += 256) {
        int lz2 = idx / 240, r = idx - lz2 * 240, ly2 = r / 20, lx2 = r - ly2 * 20;
        int gz = zB + lz2 - 2, gy = y0 + ly2 - 2, gx = x0 + lx2 - 2;
        float v = 0.f;
        if ((unsigned)gz < 64u && (unsigned)gy < 128u && (unsigned)gx < 128u)
            v = qsrc[(gz << 14) + (gy << 7) + gx];
        qf[idx] = (hf)v;
    }
    __syncthreads();

    // blur along x: qsH -> t1 (f32)
    for (int idx = tid; idx < 576; idx += 256) {
        int lz2 = idx / 48, r = idx - lz2 * 48, ly2 = r / 4, c4 = (r - ly2 * 4) * 4;
        const hf4* row = (const hf4*)&qsH[lz2][ly2][c4];   // 8B-aligned
        hf4 a = row[0], b = row[1];
        float a0 = (float)a.x, a1 = (float)a.y, a2 = (float)a.z, a3 = (float)a.w;
        float b0 = (float)b.x, b1 = (float)b.y, b2 = (float)b.z, b3 = (float)b.w;
        float4 o;
        o.x = K0 * (a0 + b0) + K1 * (a1 + a3) + K2 * a2;
        o.y = K0 * (a1 + b1) + K1 * (a2 + b0) + K2 * a3;
        o.z = K0 * (a2 + b2) + K1 * (a3 + b1) + K2 * b0;
        o.w = K0 * (a3 + b3) + K1 * (b0 + b2) + K2 * b1;
        *(float4*)&t1[lz2][ly2][c4] = o;
    }
    __syncthreads();

    // merged blur-yz (25 taps on t1) + bilateral + epilogue
    float sp[4] = {0.f, 0.f, 0.f, 0.f};
#pragma unroll
    for (int a = 0; a < 5; ++a) {
#pragma unroll
        for (int b = 0; b < 5; ++b) {
            const float kk = Kz[a] * Kz[b];
            float4 v = *(const float4*)&t1[lz + a][ly + b][lx];
            sp[0] += kk * v.x; sp[1] += kk * v.y;
            sp[2] += kk * v.z; sp[3] += kk * v.w;
        }
    }

    const unsigned int* __restrict__ Wt = W + T * TILE_WU;
    float num[4] = {0.f, 0.f, 0.f, 0.f};
#pragma unroll
    for (int r9 = 0; r9 < 9; ++r9) {
        const int dz = r9 / 3 - 1, dy = r9 % 3 - 1;
        const hf4* rp = (const hf4*)&qsH[lz + 2 + dz][ly + 2 + dy][lx];
        hf4 A = rp[0], B = rp[1];
        float q1 = (float)A.y, q2 = (float)A.z, q3 = (float)A.w;
        float q4 = (float)B.x, q5 = (float)B.y, q6 = (float)B.z;
        float qv[6] = {q1, q2, q3, q4, q5, q6};
#pragma unroll
        for (int c = 0; c < 3; ++c) {
            unsigned wv = Wt[(r9 * 3 + c) * 256 + tid];
#pragma unroll
            for (int xi = 0; xi < 4; ++xi)
                num[xi] += (float)((wv >> (8 * xi)) & 0xffu) * qv[xi + c];
        }
    }

    float4 Pv = *(const float4*)&P[g];
    float4 Mv = *(const float4*)&M[g];
    float pr4[4] = {Pv.x, Pv.y, Pv.z, Pv.w};
    float mv4[4] = {Mv.x, Mv.y, Mv.z, Mv.w};
    float qn[4];
#pragma unroll
    for (int xi = 0; xi < 4; ++xi) {
        float dn = pr4[xi] - Ac * sp[xi] - mv4[xi] * num[xi];
        qn[xi] = 1.f / (1.f + __expf(-dn));
    }

    if (!LAST) {
        *(float4*)&qdst[g] = {qn[0], qn[1], qn[2], qn[3]};
    } else {
        float4 o1 = {qn[0], qn[1], qn[2], qn[3]};
        float4 o0 = {1.f - qn[0], 1.f - qn[1], 1.f - qn[2], 1.f - qn[3]};
        *(float4*)&out[g] = o0;
        *(float4*)&out[NN + g] = o1;
        float4 fv = *(const float4*)&f1[g];
        *(float4*)&out[2 * NN + g] = fv;
    }
}

extern "C" void kernel_launch(void* const* d_in, const int* in_sizes, int n_in,
                              void* d_out, int out_size, void* d_ws, size_t ws_size,
                              hipStream_t stream)
{
    const float* img = (const float*)d_in[0];
    const float* h   = (const float*)d_in[1];
    const float* f1  = (const float*)d_in[2];
    const float* w0  = (const float*)d_in[3];
    const float* sw  = (const float*)d_in[4];
    const float* bw  = (const float*)d_in[5];
    const float* cm  = (const float*)d_in[6];
    float* out = (float*)d_out;

    float* qA = (float*)d_ws;
    float* qB = qA + (NN + PAD);
    float* P  = qB + (NN + PAD);
    float* M  = P + (NN + PAD);
    unsigned int* W = (unsigned int*)(M + (NN + PAD));   // u8 weights, 28.3 MB

    dim3 grid(WW / 16, HH / 8, DD / 8);   // 1024 blocks, shared by pre & iter
    crf_pre<<<grid, 256, 0, stream>>>(img, h, f1, w0, sw, bw, cm, qA, P, M, W);

    crf_iter<false><<<grid, 256, 0, stream>>>(qA, qB, P, M, W, sw, cm, nullptr, nullptr);
    crf_iter<false><<<grid, 256, 0, stream>>>(qB, qA, P, M, W, sw, cm, nullptr, nullptr);
    crf_iter<false><<<grid, 256, 0, stream>>>(qA, qB, P, M, W, sw, cm, nullptr, nullptr);
    crf_iter<false><<<grid, 256, 0, stream>>>(qB, qA, P, M, W, sw, cm, nullptr, nullptr);
    crf_iter<true ><<<grid, 256, 0, stream>>>(qA, nullptr, P, M, W, sw, cm, f1, out);
}